// Round 18
// baseline (152.258 us; speedup 1.0000x reference)
//
#include <hip/hip_runtime.h>

#define N_NODES 100000
#define F 128
#define NE 1600000
#define NBUCK 256
#define BSZ 391                    // nodes per bucket; 391*256 = 100096 >= N
#define CHUNK2 (NE / NBUCK)        // 6250 edges per partition chunk
#define CAP 8192                   // per-bucket region capacity (mean 6250, +24 sigma)
#define SEGCAP 16384               // LDS col-segment capacity (worst ~8K padded)
#define NGEMM ((N_NODES + 127) / 128)   // 782 gemm tiles
#define PAD8(v) (((v) + 7) & ~7)

typedef __attribute__((ext_vector_type(8))) short bf16x8;
typedef __attribute__((ext_vector_type(4))) float f32x4;

// fp32 -> bf16 round-to-nearest-even
__device__ __forceinline__ unsigned short f2bf(float f) {
    unsigned int u = __float_as_uint(f);
    return (unsigned short)((u + 0x7FFFu + ((u >> 16) & 1u)) >> 16);
}
// signed byte j of u
__device__ __forceinline__ float sb(unsigned int u, int j) {
    return (float)((int)(signed char)(u >> (8 * j)));
}

// ---------- Kernel 0: one-time prep — swizzled bf16 W^T image + zero counters/pad row ----------
__global__ __launch_bounds__(256) void prep_w(const float* __restrict__ w,
                                              ushort* __restrict__ wimg,
                                              unsigned int* __restrict__ sup8,
                                              float* __restrict__ scl,
                                              int* __restrict__ gcnt,
                                              int* __restrict__ segalloc) {
    const int t = threadIdx.x;
#pragma unroll
    for (int it = 0; it < 16; ++it) {
        const int f = it * 256 + t;
        const int c = f & 127;
        const int kq = f >> 7;
        ushort4 o;
        o.x = f2bf(w[(4 * kq + 0) * F + c]);
        o.y = f2bf(w[(4 * kq + 1) * F + c]);
        o.z = f2bf(w[(4 * kq + 2) * F + c]);
        o.w = f2bf(w[(4 * kq + 3) * F + c]);
        ((ushort4*)wimg)[c * 32 + (kq ^ ((c & 15) << 1))] = o;
    }
    if (t < 32) sup8[(size_t)N_NODES * 32 + t] = 0;   // zero pad row (128 int8)
    if (t == 0) { scl[N_NODES] = 0.f; *segalloc = 0; }
    if (t < NBUCK) gcnt[t] = 0;
}

// ---------- Fat kernel: blocks [0,NBUCK) = LDS-sorted edge partition; rest = GEMM ----------
__global__ __launch_bounds__(256) void gemm_scatter(
    const float* __restrict__ x, const ushort* __restrict__ wimg,
    unsigned int* __restrict__ sup8, float* __restrict__ scl,
    const int* __restrict__ src, const int* __restrict__ dst,
    int* __restrict__ gcnt, int* __restrict__ Psrc, unsigned short* __restrict__ Pdl) {
    __shared__ union U {
        struct { ushort xs[128 * 128]; ushort wt[128 * 128]; unsigned rmaxu[128]; } g;
        struct {
            int lsrc[CHUNK2];
            unsigned short ldl[CHUNK2];
            unsigned char lk[CHUNK2];
            int hist[NBUCK]; int off[NBUCK]; int pos[NBUCK]; int lstart[NBUCK];
        } s;
    } u;
    const int t = threadIdx.x;

    if (blockIdx.x < NBUCK) {
        // ---- scatter body: LDS bucket-sort then coalesced dump ----
        u.s.hist[t] = 0;
        u.s.pos[t] = 0;
        __syncthreads();
        const int e0 = blockIdx.x * CHUNK2;
        for (int i = t; i < CHUNK2; i += 256)
            atomicAdd(&u.s.hist[dst[e0 + i] / BSZ], 1);
        __syncthreads();
        const int h = u.s.hist[t];
        u.s.off[t] = atomicAdd(&gcnt[t], h);
        u.s.lstart[t] = h;
        __syncthreads();
        for (int o = 1; o < NBUCK; o <<= 1) {
            const int v = (t >= o) ? u.s.lstart[t - o] : 0;
            __syncthreads();
            u.s.lstart[t] += v;
            __syncthreads();
        }
        const int myexcl = u.s.lstart[t] - h;
        __syncthreads();
        u.s.lstart[t] = myexcl;
        __syncthreads();
        for (int i = t; i < CHUNK2; i += 256) {
            const int d = dst[e0 + i];
            const int k = d / BSZ;
            const int r = atomicAdd(&u.s.pos[k], 1);
            const int li = u.s.lstart[k] + r;
            u.s.lsrc[li] = src[e0 + i];
            u.s.ldl[li] = (unsigned short)(d - k * BSZ);
            u.s.lk[li] = (unsigned char)k;
        }
        __syncthreads();
        for (int i = t; i < CHUNK2; i += 256) {
            const int k = u.s.lk[i];
            const int p = k * CAP + u.s.off[k] + (i - u.s.lstart[k]);
            Psrc[p] = u.s.lsrc[i];
            Pdl[p] = u.s.ldl[i];
        }
        return;
    }

    // ---- gemm body ----
    ushort* xs = u.g.xs;
    ushort* wt = u.g.wt;
    const int rbase = (blockIdx.x - NBUCK) * 128;

#pragma unroll
    for (int i = 0; i < 8; ++i)
        ((float4*)wt)[i * 256 + t] = ((const float4*)wimg)[i * 256 + t];
#pragma unroll
    for (int it = 0; it < 16; ++it) {
        const int f = it * 256 + t;
        const int r = f >> 5;
        const int cg = f & 31;
        const int gr = rbase + r;
        float4 v = make_float4(0.f, 0.f, 0.f, 0.f);
        if (gr < N_NODES) v = ((const float4*)x)[(long long)gr * 32 + cg];
        ushort4 o;
        o.x = f2bf(v.x); o.y = f2bf(v.y); o.z = f2bf(v.z); o.w = f2bf(v.w);
        ((ushort4*)xs)[r * 32 + (cg ^ ((r & 15) << 1))] = o;
    }
    __syncthreads();

    const int wid = t >> 6;
    const int lane = t & 63;
    const int wr = wid >> 1;
    const int wc = wid & 1;
    const int l16 = lane & 15;
    const int kg = lane >> 4;

    f32x4 acc[4][4] = {};
    const bf16x8* xs8 = (const bf16x8*)xs;
    const bf16x8* wt8 = (const bf16x8*)wt;

#pragma unroll
    for (int ks = 0; ks < 4; ++ks) {
        const int k8 = ks * 4 + kg;
        bf16x8 a[4], bb[4];
#pragma unroll
        for (int mi = 0; mi < 4; ++mi) {
            const int r = wr * 64 + mi * 16 + l16;
            a[mi] = xs8[r * 16 + (k8 ^ (r & 15))];
        }
#pragma unroll
        for (int ni = 0; ni < 4; ++ni) {
            const int c = wc * 64 + ni * 16 + l16;
            bb[ni] = wt8[c * 16 + (k8 ^ (c & 15))];
        }
        // swapped operands: D = (x-block . W-block)^T -> row in l16, cols in regs
#pragma unroll
        for (int mi = 0; mi < 4; ++mi)
#pragma unroll
            for (int ni = 0; ni < 4; ++ni)
                acc[mi][ni] = __builtin_amdgcn_mfma_f32_16x16x32_bf16(
                    bb[ni], a[mi], acc[mi][ni], 0, 0, 0);
    }

    // ---- int8 quantization epilogue: per-row max via LDS atomicMax (f32>=0 as uint) ----
    float mx[4];
#pragma unroll
    for (int mi = 0; mi < 4; ++mi) {
        float m = 0.f;
#pragma unroll
        for (int ni = 0; ni < 4; ++ni)
#pragma unroll
            for (int j = 0; j < 4; ++j)
                m = fmaxf(m, fabsf(acc[mi][ni][j]));
        mx[mi] = m;
    }
    if (t < 128) u.g.rmaxu[t] = 0u;
    __syncthreads();
#pragma unroll
    for (int mi = 0; mi < 4; ++mi)
        atomicMax(&u.g.rmaxu[wr * 64 + mi * 16 + l16], __float_as_uint(mx[mi]));
    __syncthreads();

#pragma unroll
    for (int mi = 0; mi < 4; ++mi) {
        const int lr = wr * 64 + mi * 16 + l16;
        const int r = rbase + lr;
        if (r < N_NODES) {
            const float rm = __uint_as_float(u.g.rmaxu[lr]);
            const float inv = rm > 0.f ? 127.0f / rm : 0.f;
            if (wc == 0 && kg == 0) scl[r] = rm * (1.0f / 127.0f);
#pragma unroll
            for (int ni = 0; ni < 4; ++ni) {
                int q0 = (int)rintf(acc[mi][ni][0] * inv);
                int q1 = (int)rintf(acc[mi][ni][1] * inv);
                int q2 = (int)rintf(acc[mi][ni][2] * inv);
                int q3 = (int)rintf(acc[mi][ni][3] * inv);
                const unsigned int packed = (q0 & 255) | ((q1 & 255) << 8) |
                                            ((q2 & 255) << 16) | ((q3 & 255) << 24);
                sup8[(long long)r * 32 + wc * 16 + ni * 4 + kg] = packed;
            }
        }
    }
}

// ---------- B: per-bucket deg count + local padded scan + bump-allocated CSR fill ----------
__global__ __launch_bounds__(1024) void col_fill2(const int* __restrict__ Psrc,
                                                  const unsigned short* __restrict__ Pdl,
                                                  const int* __restrict__ gcnt,
                                                  int* __restrict__ segalloc,
                                                  int* __restrict__ deg,
                                                  int* __restrict__ row_ptr,
                                                  int* __restrict__ col) {
    __shared__ int buf[SEGCAP];    // 64 KB
    __shared__ int c[BSZ];
    __shared__ int cnt[BSZ];
    __shared__ int sh[512];
    __shared__ int rp[BSZ];
    __shared__ int segbase_s;
    const int k = blockIdx.x;
    const int t = threadIdx.x;
    const int n0 = k * BSZ;
    const int nn = min(N_NODES - n0, BSZ);
    for (int i = t; i < BSZ; i += 1024) { c[i] = 0; cnt[i] = 0; }
    __syncthreads();
    const int e0 = k * CAP;
    const int ne = gcnt[k];
    for (int i = t; i < ne; i += 1024) atomicAdd(&c[Pdl[e0 + i]], 1);
    __syncthreads();
    int myp = 0;
    if (t < 512) { myp = (t < nn) ? PAD8(c[t]) : 0; sh[t] = myp; }
    __syncthreads();
    for (int off = 1; off < 512; off <<= 1) {
        int u = 0;
        if (t < 512 && t >= off) u = sh[t - off];
        __syncthreads();
        if (t < 512) sh[t] += u;
        __syncthreads();
    }
    if (t == 511) segbase_s = atomicAdd(segalloc, sh[511]);
    __syncthreads();
    const int segbase = segbase_s;
    const int seglen = sh[511];
    if (t < nn) {
        const int start = segbase + sh[t] - myp;
        rp[t] = start;
        row_ptr[n0 + t] = start;
        deg[n0 + t] = c[t];
    }
    __syncthreads();
    for (int i = t; i < seglen; i += 1024) buf[i] = N_NODES;
    __syncthreads();
    for (int i = t; i < ne; i += 1024) {
        const int dl = Pdl[e0 + i];
        const int r = atomicAdd(&cnt[dl], 1);
        buf[rp[dl] - segbase + r] = Psrc[e0 + i];
    }
    __syncthreads();
    for (int i = t; i < (seglen >> 2); i += 1024)
        ((int4*)(col + segbase))[i] = ((const int4*)buf)[i];
}

// ---------- aggregate: int8 gather, 8 row-slots x 8 fq, 4-deep 32-edge groups ----------
__global__ __launch_bounds__(256) void aggregate_kernel(
    const unsigned int* __restrict__ sup8,
    const float* __restrict__ scl,
    const int* __restrict__ row_ptr,
    const int* __restrict__ degv,
    const int* __restrict__ col,
    const float* __restrict__ b,
    float* __restrict__ out) {
    const int wid = threadIdx.x >> 6;
    const int lane = threadIdx.x & 63;
    const int node = blockIdx.x * 4 + wid;
    if (node >= N_NODES) return;

    const int rs = lane >> 3;   // row slot 0..7
    const int fq = lane & 7;    // uint4 index within 128B row (16 features)

    const int beg = row_ptr[node];
    const int dg = degv[node];
    const int end = beg + PAD8(dg);

    const uint4* sp = (const uint4*)sup8;   // row r = sp[r*8 + fq]

    float acc[16] = {};
    for (int base = beg; base < end; base += 64) {
        const int rem = end - base;
        const int m = rem < 64 ? rem : 64;                 // multiple of 8
        const int mycol = (lane < m) ? col[base + lane] : 0;
        int j = 0;
        for (; j + 32 <= m; j += 32) {
            uint4 v[4];
            float sc[4];
#pragma unroll
            for (int q = 0; q < 4; ++q) {
                const int s = __shfl(mycol, j + q * 8 + rs);
                v[q] = sp[(long long)s * 8 + fq];
                sc[q] = scl[s];
            }
#pragma unroll
            for (int q = 0; q < 4; ++q) {
#pragma unroll
                for (int y = 0; y < 4; ++y) {
                    const unsigned int uv = (y == 0) ? v[q].x : (y == 1) ? v[q].y
                                          : (y == 2) ? v[q].z : v[q].w;
                    acc[y * 4 + 0] = fmaf(sc[q], sb(uv, 0), acc[y * 4 + 0]);
                    acc[y * 4 + 1] = fmaf(sc[q], sb(uv, 1), acc[y * 4 + 1]);
                    acc[y * 4 + 2] = fmaf(sc[q], sb(uv, 2), acc[y * 4 + 2]);
                    acc[y * 4 + 3] = fmaf(sc[q], sb(uv, 3), acc[y * 4 + 3]);
                }
            }
        }
        for (; j < m; j += 8) {                            // 8-edge tail groups
            const int s = __shfl(mycol, j + rs);
            const uint4 v = sp[(long long)s * 8 + fq];
            const float sc = scl[s];
#pragma unroll
            for (int y = 0; y < 4; ++y) {
                const unsigned int uv = (y == 0) ? v.x : (y == 1) ? v.y
                                      : (y == 2) ? v.z : v.w;
                acc[y * 4 + 0] = fmaf(sc, sb(uv, 0), acc[y * 4 + 0]);
                acc[y * 4 + 1] = fmaf(sc, sb(uv, 1), acc[y * 4 + 1]);
                acc[y * 4 + 2] = fmaf(sc, sb(uv, 2), acc[y * 4 + 2]);
                acc[y * 4 + 3] = fmaf(sc, sb(uv, 3), acc[y * 4 + 3]);
            }
        }
    }
    // reduce across the 8 row slots FIRST...
#pragma unroll
    for (int i = 0; i < 16; ++i) {
        acc[i] += __shfl_xor(acc[i], 8);
        acc[i] += __shfl_xor(acc[i], 16);
        acc[i] += __shfl_xor(acc[i], 32);
    }
    // ...THEN add self-loop exactly once
    {
        const uint4 v = sp[(long long)node * 8 + fq];
        const float sc = scl[node];
#pragma unroll
        for (int y = 0; y < 4; ++y) {
            const unsigned int uv = (y == 0) ? v.x : (y == 1) ? v.y
                                  : (y == 2) ? v.z : v.w;
            acc[y * 4 + 0] = fmaf(sc, sb(uv, 0), acc[y * 4 + 0]);
            acc[y * 4 + 1] = fmaf(sc, sb(uv, 1), acc[y * 4 + 1]);
            acc[y * 4 + 2] = fmaf(sc, sb(uv, 2), acc[y * 4 + 2]);
            acc[y * 4 + 3] = fmaf(sc, sb(uv, 3), acc[y * 4 + 3]);
        }
    }
    const float inv = 1.0f / (float)(dg + 1);
    if (rs == 0) {
        float4* o4 = (float4*)out;
#pragma unroll
        for (int j = 0; j < 4; ++j) {
            const float4 bb = ((const float4*)b)[fq * 4 + j];
            float4 r;
            r.x = acc[j * 4 + 0] * inv + bb.x;
            r.y = acc[j * 4 + 1] * inv + bb.y;
            r.z = acc[j * 4 + 2] * inv + bb.z;
            r.w = acc[j * 4 + 3] * inv + bb.w;
            o4[(long long)node * 32 + fq * 4 + j] = r;
        }
    }
}

extern "C" void kernel_launch(void* const* d_in, const int* in_sizes, int n_in,
                              void* d_out, int out_size, void* d_ws, size_t ws_size,
                              hipStream_t stream) {
    const float* x = (const float*)d_in[0];
    const int* src = (const int*)d_in[1];
    const int* dst = (const int*)d_in[2];
    const float* w = (const float*)d_in[3];
    const float* b = (const float*)d_in[4];
    float* out = (float*)d_out;

    // Workspace: sup8 12.8 | scl .4 | deg .4 | row_ptr .4 | col 9.2 | Psrc 8.4 | Pdl 4.2 | wimg | ctrs
    char* p = (char*)d_ws;
    unsigned int* sup8 = (unsigned int*)p;  p += (((size_t)(N_NODES + 1)) * 32 * sizeof(unsigned int) + 15) & ~15ULL;
    float* scl = (float*)p;      p += (((size_t)N_NODES + 1) * sizeof(float) + 15) & ~15ULL;
    int* deg = (int*)p;          p += ((size_t)N_NODES * sizeof(int) + 15) & ~15ULL;
    int* row_ptr = (int*)p;      p += ((size_t)N_NODES * sizeof(int) + 15) & ~15ULL;
    int* col = (int*)p;          p += ((size_t)(NE + 7 * N_NODES) * sizeof(int) + 15) & ~15ULL;
    int* Psrc = (int*)p;         p += ((size_t)NBUCK * CAP * sizeof(int) + 15) & ~15ULL;
    unsigned short* Pdl = (unsigned short*)p;  p += ((size_t)NBUCK * CAP * sizeof(unsigned short) + 15) & ~15ULL;
    ushort* wimg = (ushort*)p;   p += ((size_t)F * F * sizeof(ushort) + 15) & ~15ULL;
    int* gcnt = (int*)p;         p += ((size_t)NBUCK * sizeof(int) + 15) & ~15ULL;
    int* segalloc = (int*)p;

    prep_w<<<1, 256, 0, stream>>>(w, wimg, sup8, scl, gcnt, segalloc);
    gemm_scatter<<<NBUCK + NGEMM, 256, 0, stream>>>(x, wimg, sup8, scl, src, dst, gcnt, Psrc, Pdl);
    col_fill2<<<NBUCK, 1024, 0, stream>>>(Psrc, Pdl, gcnt, segalloc, deg, row_ptr, col);
    aggregate_kernel<<<(N_NODES + 3) / 4, 256, 0, stream>>>(sup8, scl, row_ptr, deg, col, b, out);
}

// Round 19
// 122.550 us; speedup vs baseline: 1.2424x; 1.2424x over previous
//
#include <hip/hip_runtime.h>

#define N_NODES 100000
#define F 128
#define NE 1600000
#define NBUCK 256
#define BSZ 391                    // nodes per bucket; 391*256 = 100096 >= N
#define CHUNK2 (NE / NBUCK)        // 6250 edges per partition chunk
#define CAP 8192                   // per-bucket region capacity (mean 6250, +24 sigma)
#define SEGCAP 16384               // LDS col-segment capacity (worst ~8K padded)
#define NGEMM ((N_NODES + 127) / 128)   // 782 gemm tiles
#define PAD8(v) (((v) + 7) & ~7)

typedef __attribute__((ext_vector_type(8))) short bf16x8;
typedef __attribute__((ext_vector_type(4))) float f32x4;

// fp32 -> bf16 round-to-nearest-even
__device__ __forceinline__ unsigned short f2bf(float f) {
    unsigned int u = __float_as_uint(f);
    return (unsigned short)((u + 0x7FFFu + ((u >> 16) & 1u)) >> 16);
}
__device__ __forceinline__ float blo(unsigned int v) { return __uint_as_float(v << 16); }
__device__ __forceinline__ float bhi(unsigned int v) { return __uint_as_float(v & 0xFFFF0000u); }

// ---------- Kernel 0: one-time prep — swizzled bf16 W^T image + zero counters/pad row ----------
__global__ __launch_bounds__(256) void prep_w(const float* __restrict__ w,
                                              ushort* __restrict__ wimg,
                                              ushort* __restrict__ sup,
                                              int* __restrict__ gcnt,
                                              int* __restrict__ segalloc) {
    const int t = threadIdx.x;
#pragma unroll
    for (int it = 0; it < 16; ++it) {
        const int f = it * 256 + t;
        const int c = f & 127;
        const int kq = f >> 7;
        ushort4 o;
        o.x = f2bf(w[(4 * kq + 0) * F + c]);
        o.y = f2bf(w[(4 * kq + 1) * F + c]);
        o.z = f2bf(w[(4 * kq + 2) * F + c]);
        o.w = f2bf(w[(4 * kq + 3) * F + c]);
        ((ushort4*)wimg)[c * 32 + (kq ^ ((c & 15) << 1))] = o;
    }
    if (t < 128) sup[(size_t)N_NODES * F + t] = 0;   // zero pad row
    if (t < NBUCK) gcnt[t] = 0;
    if (t == 0) *segalloc = 0;
}

// ---------- Fat kernel: blocks [0,NBUCK) = LDS-sorted edge partition; rest = GEMM ----------
__global__ __launch_bounds__(256) void gemm_scatter(
    const float* __restrict__ x, const ushort* __restrict__ wimg, ushort* __restrict__ sup,
    const int* __restrict__ src, const int* __restrict__ dst,
    int* __restrict__ gcnt, int* __restrict__ Psrc, unsigned short* __restrict__ Pdl) {
    __shared__ union U {
        struct { ushort xs[128 * 128]; ushort wt[128 * 128]; } g;   // 64 KB (gemm)
        struct {                                                    // ~48 KB (scatter)
            int lsrc[CHUNK2];
            unsigned short ldl[CHUNK2];
            unsigned char lk[CHUNK2];
            int hist[NBUCK]; int off[NBUCK]; int pos[NBUCK]; int lstart[NBUCK];
        } s;
    } u;
    const int t = threadIdx.x;

    if (blockIdx.x < NBUCK) {
        // ---- scatter body: LDS bucket-sort then coalesced dump ----
        u.s.hist[t] = 0;
        u.s.pos[t] = 0;
        __syncthreads();
        const int e0 = blockIdx.x * CHUNK2;
        // pass 1: histogram
        for (int i = t; i < CHUNK2; i += 256)
            atomicAdd(&u.s.hist[dst[e0 + i] / BSZ], 1);
        __syncthreads();
        const int h = u.s.hist[t];
        u.s.off[t] = atomicAdd(&gcnt[t], h);     // reserve contiguous run
        // exclusive scan of hist -> lstart
        u.s.lstart[t] = h;
        __syncthreads();
        for (int o = 1; o < NBUCK; o <<= 1) {
            const int v = (t >= o) ? u.s.lstart[t - o] : 0;
            __syncthreads();
            u.s.lstart[t] += v;
            __syncthreads();
        }
        const int myexcl = u.s.lstart[t] - h;
        __syncthreads();
        u.s.lstart[t] = myexcl;
        __syncthreads();
        // pass 2: sort into LDS
        for (int i = t; i < CHUNK2; i += 256) {
            const int d = dst[e0 + i];
            const int k = d / BSZ;
            const int r = atomicAdd(&u.s.pos[k], 1);
            const int li = u.s.lstart[k] + r;
            u.s.lsrc[li] = src[e0 + i];
            u.s.ldl[li] = (unsigned short)(d - k * BSZ);
            u.s.lk[li] = (unsigned char)k;
        }
        __syncthreads();
        // dump: consecutive i in a run -> consecutive global addrs (coalesced)
        for (int i = t; i < CHUNK2; i += 256) {
            const int k = u.s.lk[i];
            const int p = k * CAP + u.s.off[k] + (i - u.s.lstart[k]);
            Psrc[p] = u.s.lsrc[i];
            Pdl[p] = u.s.ldl[i];
        }
        return;
    }

    // ---- gemm body ----
    ushort* xs = u.g.xs;
    ushort* wt = u.g.wt;
    const int rbase = (blockIdx.x - NBUCK) * 128;

#pragma unroll
    for (int i = 0; i < 8; ++i)
        ((float4*)wt)[i * 256 + t] = ((const float4*)wimg)[i * 256 + t];
#pragma unroll
    for (int it = 0; it < 16; ++it) {
        const int f = it * 256 + t;
        const int r = f >> 5;
        const int cg = f & 31;
        const int gr = rbase + r;
        float4 v = make_float4(0.f, 0.f, 0.f, 0.f);
        if (gr < N_NODES) v = ((const float4*)x)[(long long)gr * 32 + cg];
        ushort4 o;
        o.x = f2bf(v.x); o.y = f2bf(v.y); o.z = f2bf(v.z); o.w = f2bf(v.w);
        ((ushort4*)xs)[r * 32 + (cg ^ ((r & 15) << 1))] = o;
    }
    __syncthreads();

    const int wid = t >> 6;
    const int lane = t & 63;
    const int wr = wid >> 1;
    const int wc = wid & 1;
    const int l16 = lane & 15;
    const int kg = lane >> 4;

    f32x4 acc[4][4] = {};
    const bf16x8* xs8 = (const bf16x8*)xs;
    const bf16x8* wt8 = (const bf16x8*)wt;

#pragma unroll
    for (int ks = 0; ks < 4; ++ks) {
        const int k8 = ks * 4 + kg;
        bf16x8 a[4], bb[4];
#pragma unroll
        for (int mi = 0; mi < 4; ++mi) {
            const int r = wr * 64 + mi * 16 + l16;
            a[mi] = xs8[r * 16 + (k8 ^ (r & 15))];
        }
#pragma unroll
        for (int ni = 0; ni < 4; ++ni) {
            const int c = wc * 64 + ni * 16 + l16;
            bb[ni] = wt8[c * 16 + (k8 ^ (c & 15))];
        }
        // swapped operands: D = (x-block . W-block)^T -> row in l16, cols in regs
#pragma unroll
        for (int mi = 0; mi < 4; ++mi)
#pragma unroll
            for (int ni = 0; ni < 4; ++ni)
                acc[mi][ni] = __builtin_amdgcn_mfma_f32_16x16x32_bf16(
                    bb[ni], a[mi], acc[mi][ni], 0, 0, 0);
    }

#pragma unroll
    for (int mi = 0; mi < 4; ++mi) {
        const int r = rbase + wr * 64 + mi * 16 + l16;
        if (r < N_NODES) {
#pragma unroll
            for (int ni = 0; ni < 4; ++ni) {
                ushort4 o;
                o.x = f2bf(acc[mi][ni][0]);
                o.y = f2bf(acc[mi][ni][1]);
                o.z = f2bf(acc[mi][ni][2]);
                o.w = f2bf(acc[mi][ni][3]);
                const long long idx = ((long long)r * F + wc * 64 + ni * 16 + kg * 4) >> 2;
                ((ushort4*)sup)[idx] = o;
            }
        }
    }
}

// ---------- B: per-bucket deg count + local padded scan + bump-allocated CSR fill ----------
__global__ __launch_bounds__(1024) void col_fill2(const int* __restrict__ Psrc,
                                                  const unsigned short* __restrict__ Pdl,
                                                  const int* __restrict__ gcnt,
                                                  int* __restrict__ segalloc,
                                                  int* __restrict__ deg,
                                                  int* __restrict__ row_ptr,
                                                  int* __restrict__ col) {
    __shared__ int buf[SEGCAP];    // 64 KB
    __shared__ int c[BSZ];         // degree counts
    __shared__ int cnt[BSZ];       // rank counters
    __shared__ int sh[512];        // scan
    __shared__ int rp[BSZ];        // absolute segment start per node
    __shared__ int segbase_s;
    const int k = blockIdx.x;
    const int t = threadIdx.x;
    const int n0 = k * BSZ;
    const int nn = min(N_NODES - n0, BSZ);
    for (int i = t; i < BSZ; i += 1024) { c[i] = 0; cnt[i] = 0; }
    __syncthreads();
    const int e0 = k * CAP;
    const int ne = gcnt[k];
    for (int i = t; i < ne; i += 1024) atomicAdd(&c[Pdl[e0 + i]], 1);
    __syncthreads();
    // inclusive scan of padded degrees over 512 slots (nn <= 391)
    int myp = 0;
    if (t < 512) { myp = (t < nn) ? PAD8(c[t]) : 0; sh[t] = myp; }
    __syncthreads();
    for (int off = 1; off < 512; off <<= 1) {
        int u = 0;
        if (t < 512 && t >= off) u = sh[t - off];
        __syncthreads();
        if (t < 512) sh[t] += u;
        __syncthreads();
    }
    if (t == 511) segbase_s = atomicAdd(segalloc, sh[511]);
    __syncthreads();
    const int segbase = segbase_s;
    const int seglen = sh[511];                   // multiple of 8
    if (t < nn) {
        const int start = segbase + sh[t] - myp;  // exclusive prefix
        rp[t] = start;
        row_ptr[n0 + t] = start;
        deg[n0 + t] = c[t];
    }
    __syncthreads();
    for (int i = t; i < seglen; i += 1024) buf[i] = N_NODES;   // pad = zero row
    __syncthreads();
    for (int i = t; i < ne; i += 1024) {
        const int dl = Pdl[e0 + i];
        const int r = atomicAdd(&cnt[dl], 1);
        buf[rp[dl] - segbase + r] = Psrc[e0 + i];
    }
    __syncthreads();
    for (int i = t; i < (seglen >> 2); i += 1024)
        ((int4*)(col + segbase))[i] = ((const int4*)buf)[i];
}

// ---------- Kernel 5: gather-aggregate, branchless; end derived from PAD8(deg) ----------
__global__ __launch_bounds__(256) void aggregate_kernel(
    const ushort* __restrict__ sup,
    const int* __restrict__ row_ptr,
    const int* __restrict__ degv,
    const int* __restrict__ col,
    const float* __restrict__ b,
    float* __restrict__ out) {
    const int wid = threadIdx.x >> 6;
    const int lane = threadIdx.x & 63;
    const int node = blockIdx.x * 4 + wid;
    if (node >= N_NODES) return;

    const int rs = lane >> 4;   // row slot 0..3
    const int fq = lane & 15;   // feature quad

    const int beg = row_ptr[node];
    const int dg = degv[node];
    const int end = beg + PAD8(dg);

    const uint4* sp = (const uint4*)sup;

    float acc[8] = {};
    for (int base = beg; base < end; base += 64) {
        const int rem = end - base;
        const int m = rem < 64 ? rem : 64;                 // multiple of 8
        const int mycol = (lane < m) ? col[base + lane] : 0;
        const int ng16 = m >> 4;
        for (int g = 0; g < ng16; ++g) {
            uint4 v[4];
#pragma unroll
            for (int q = 0; q < 4; ++q) {
                const int s = __shfl(mycol, g * 16 + q * 4 + rs);
                v[q] = sp[(long long)s * 16 + fq];         // pads read zero row
            }
#pragma unroll
            for (int q = 0; q < 4; ++q) {
                acc[0] += blo(v[q].x); acc[1] += bhi(v[q].x);
                acc[2] += blo(v[q].y); acc[3] += bhi(v[q].y);
                acc[4] += blo(v[q].z); acc[5] += bhi(v[q].z);
                acc[6] += blo(v[q].w); acc[7] += bhi(v[q].w);
            }
        }
        if (m & 8) {                                       // 8-edge tail group
            uint4 v[2];
#pragma unroll
            for (int q = 0; q < 2; ++q) {
                const int s = __shfl(mycol, (ng16 << 4) + q * 4 + rs);
                v[q] = sp[(long long)s * 16 + fq];
            }
#pragma unroll
            for (int q = 0; q < 2; ++q) {
                acc[0] += blo(v[q].x); acc[1] += bhi(v[q].x);
                acc[2] += blo(v[q].y); acc[3] += bhi(v[q].y);
                acc[4] += blo(v[q].z); acc[5] += bhi(v[q].z);
                acc[6] += blo(v[q].w); acc[7] += bhi(v[q].w);
            }
        }
    }
    // reduce across the 4 row slots FIRST...
#pragma unroll
    for (int i = 0; i < 8; ++i) {
        acc[i] += __shfl_xor(acc[i], 16);
        acc[i] += __shfl_xor(acc[i], 32);
    }
    // ...THEN add self-loop exactly once
    {
        const uint4 v = sp[(long long)node * 16 + fq];
        acc[0] += blo(v.x); acc[1] += bhi(v.x);
        acc[2] += blo(v.y); acc[3] += bhi(v.y);
        acc[4] += blo(v.z); acc[5] += bhi(v.z);
        acc[6] += blo(v.w); acc[7] += bhi(v.w);
    }
    const float inv = 1.0f / (float)(dg + 1);
    const float4 b0 = ((const float4*)b)[fq * 2];
    const float4 b1 = ((const float4*)b)[fq * 2 + 1];
    if (rs == 0) {
        float4 r0, r1;
        r0.x = acc[0] * inv + b0.x; r0.y = acc[1] * inv + b0.y;
        r0.z = acc[2] * inv + b0.z; r0.w = acc[3] * inv + b0.w;
        r1.x = acc[4] * inv + b1.x; r1.y = acc[5] * inv + b1.y;
        r1.z = acc[6] * inv + b1.z; r1.w = acc[7] * inv + b1.w;
        float4* o4 = (float4*)out;
        o4[(long long)node * 32 + fq * 2] = r0;
        o4[(long long)node * 32 + fq * 2 + 1] = r1;
    }
}

extern "C" void kernel_launch(void* const* d_in, const int* in_sizes, int n_in,
                              void* d_out, int out_size, void* d_ws, size_t ws_size,
                              hipStream_t stream) {
    const float* x = (const float*)d_in[0];
    const int* src = (const int*)d_in[1];
    const int* dst = (const int*)d_in[2];
    const float* w = (const float*)d_in[3];
    const float* b = (const float*)d_in[4];
    float* out = (float*)d_out;

    // Workspace (~49 MB): sup 25.6 | deg .4 | row_ptr .4 | col 9.2 | Psrc 8.4 | Pdl 4.2 | wimg | ctrs
    char* p = (char*)d_ws;
    ushort* sup = (ushort*)p;    p += (((size_t)(N_NODES + 1)) * F * sizeof(ushort) + 15) & ~15ULL;
    int* deg = (int*)p;          p += ((size_t)N_NODES * sizeof(int) + 15) & ~15ULL;
    int* row_ptr = (int*)p;      p += ((size_t)N_NODES * sizeof(int) + 15) & ~15ULL;
    int* col = (int*)p;          p += ((size_t)(NE + 7 * N_NODES) * sizeof(int) + 15) & ~15ULL;
    int* Psrc = (int*)p;         p += ((size_t)NBUCK * CAP * sizeof(int) + 15) & ~15ULL;
    unsigned short* Pdl = (unsigned short*)p;  p += ((size_t)NBUCK * CAP * sizeof(unsigned short) + 15) & ~15ULL;
    ushort* wimg = (ushort*)p;   p += ((size_t)F * F * sizeof(ushort) + 15) & ~15ULL;
    int* gcnt = (int*)p;         p += ((size_t)NBUCK * sizeof(int) + 15) & ~15ULL;
    int* segalloc = (int*)p;

    prep_w<<<1, 256, 0, stream>>>(w, wimg, sup, gcnt, segalloc);
    gemm_scatter<<<NBUCK + NGEMM, 256, 0, stream>>>(x, wimg, sup, src, dst, gcnt, Psrc, Pdl);
    col_fill2<<<NBUCK, 1024, 0, stream>>>(Psrc, Pdl, gcnt, segalloc, deg, row_ptr, col);
    aggregate_kernel<<<(N_NODES + 3) / 4, 256, 0, stream>>>(sup, row_ptr, deg, col, b, out);
}

// Round 20
// 118.831 us; speedup vs baseline: 1.2813x; 1.0313x over previous
//
#include <hip/hip_runtime.h>

#define N_NODES 100000
#define F 128
#define NE 1600000
#define NBUCK 256
#define BSZ 391                    // nodes per bucket; 391*256 = 100096 >= N
#define CHUNK2 (NE / NBUCK)        // 6250 edges per partition chunk
#define CAP 8192                   // per-bucket region capacity (mean 6250, +24 sigma)
#define SEGCAP 16384               // LDS col-segment capacity (worst ~8K padded)
#define NGEMM ((N_NODES + 127) / 128)   // 782 gemm tiles
#define PAD8(v) (((v) + 7) & ~7)

typedef __attribute__((ext_vector_type(8))) short bf16x8;
typedef __attribute__((ext_vector_type(4))) float f32x4;

// fp32 -> bf16 round-to-nearest-even
__device__ __forceinline__ unsigned short f2bf(float f) {
    unsigned int u = __float_as_uint(f);
    return (unsigned short)((u + 0x7FFFu + ((u >> 16) & 1u)) >> 16);
}
__device__ __forceinline__ float blo(unsigned int v) { return __uint_as_float(v << 16); }
__device__ __forceinline__ float bhi(unsigned int v) { return __uint_as_float(v & 0xFFFF0000u); }

// ---------- Kernel 0: one-time prep — swizzled bf16 W^T image + zero counters/pad row ----------
__global__ __launch_bounds__(256) void prep_w(const float* __restrict__ w,
                                              ushort* __restrict__ wimg,
                                              ushort* __restrict__ sup,
                                              int* __restrict__ gcnt,
                                              int* __restrict__ segalloc) {
    const int t = threadIdx.x;
#pragma unroll
    for (int it = 0; it < 16; ++it) {
        const int f = it * 256 + t;
        const int c = f & 127;
        const int kq = f >> 7;
        ushort4 o;
        o.x = f2bf(w[(4 * kq + 0) * F + c]);
        o.y = f2bf(w[(4 * kq + 1) * F + c]);
        o.z = f2bf(w[(4 * kq + 2) * F + c]);
        o.w = f2bf(w[(4 * kq + 3) * F + c]);
        ((ushort4*)wimg)[c * 32 + (kq ^ ((c & 15) << 1))] = o;
    }
    if (t < 128) sup[(size_t)N_NODES * F + t] = 0;   // zero pad row
    if (t < NBUCK) gcnt[t] = 0;
    if (t == 0) *segalloc = 0;
}

// ---------- Fat kernel: blocks [0,NBUCK) = edge partition (u16 index sort); rest = GEMM ----------
__global__ __launch_bounds__(256) void gemm_scatter(
    const float* __restrict__ x, const ushort* __restrict__ wimg, ushort* __restrict__ sup,
    const int* __restrict__ src, const int* __restrict__ dst,
    int* __restrict__ gcnt, int* __restrict__ Psrc, unsigned short* __restrict__ Pdl) {
    __shared__ union U {
        struct { ushort xs[128 * 128]; } g;                          // 32 KB (gemm)
        struct {                                                     // ~16.6 KB (scatter)
            unsigned short eidx[CHUNK2];
            int hist[NBUCK]; int off[NBUCK]; int pos[NBUCK]; int lstart[NBUCK];
        } s;
    } u;
    const int t = threadIdx.x;

    if (blockIdx.x < NBUCK) {
        // ---- scatter body: LDS index-sort then coalesced dump ----
        u.s.hist[t] = 0;
        u.s.pos[t] = 0;
        __syncthreads();
        const int e0 = blockIdx.x * CHUNK2;
        // pass 1: histogram
        for (int i = t; i < CHUNK2; i += 256)
            atomicAdd(&u.s.hist[dst[e0 + i] / BSZ], 1);
        __syncthreads();
        const int h = u.s.hist[t];
        u.s.off[t] = atomicAdd(&gcnt[t], h);     // reserve contiguous run
        // exclusive scan of hist -> lstart
        u.s.lstart[t] = h;
        __syncthreads();
        for (int o = 1; o < NBUCK; o <<= 1) {
            const int v = (t >= o) ? u.s.lstart[t - o] : 0;
            __syncthreads();
            u.s.lstart[t] += v;
            __syncthreads();
        }
        const int myexcl = u.s.lstart[t] - h;
        __syncthreads();
        u.s.lstart[t] = myexcl;
        __syncthreads();
        // pass 2: sort edge indices into LDS (dst re-read is L1/L2-resident)
        for (int i = t; i < CHUNK2; i += 256) {
            const int d = dst[e0 + i];
            const int k = d / BSZ;
            const int r = atomicAdd(&u.s.pos[k], 1);
            u.s.eidx[u.s.lstart[k] + r] = (unsigned short)i;
        }
        __syncthreads();
        // dump: consecutive i in a run -> consecutive global addrs (coalesced);
        // src/dst re-reads hit the chunk's cached 50 KB window
        for (int i = t; i < CHUNK2; i += 256) {
            const int idx = u.s.eidx[i];
            const int d = dst[e0 + idx];
            const int k = d / BSZ;
            const int p = k * CAP + u.s.off[k] + (i - u.s.lstart[k]);
            Psrc[p] = src[e0 + idx];
            Pdl[p] = (unsigned short)(d - k * BSZ);
        }
        return;
    }

    // ---- gemm body: xs in LDS; W fragments read directly from L2-resident wimg ----
    ushort* xs = u.g.xs;
    const int rbase = (blockIdx.x - NBUCK) * 128;

#pragma unroll
    for (int it = 0; it < 16; ++it) {
        const int f = it * 256 + t;
        const int r = f >> 5;
        const int cg = f & 31;
        const int gr = rbase + r;
        float4 v = make_float4(0.f, 0.f, 0.f, 0.f);
        if (gr < N_NODES) v = ((const float4*)x)[(long long)gr * 32 + cg];
        ushort4 o;
        o.x = f2bf(v.x); o.y = f2bf(v.y); o.z = f2bf(v.z); o.w = f2bf(v.w);
        ((ushort4*)xs)[r * 32 + (cg ^ ((r & 15) << 1))] = o;
    }
    __syncthreads();

    const int wid = t >> 6;
    const int lane = t & 63;
    const int wr = wid >> 1;
    const int wc = wid & 1;
    const int l16 = lane & 15;
    const int kg = lane >> 4;

    f32x4 acc[4][4] = {};
    const bf16x8* xs8 = (const bf16x8*)xs;
    const bf16x8* wt8 = (const bf16x8*)wimg;   // global, L2-resident (32 KB shared by all blocks)

#pragma unroll
    for (int ks = 0; ks < 4; ++ks) {
        const int k8 = ks * 4 + kg;
        bf16x8 a[4], bb[4];
#pragma unroll
        for (int mi = 0; mi < 4; ++mi) {
            const int r = wr * 64 + mi * 16 + l16;
            a[mi] = xs8[r * 16 + (k8 ^ (r & 15))];
        }
#pragma unroll
        for (int ni = 0; ni < 4; ++ni) {
            const int c = wc * 64 + ni * 16 + l16;
            bb[ni] = wt8[c * 16 + (k8 ^ (c & 15))];
        }
        // swapped operands: D = (x-block . W-block)^T -> row in l16, cols in regs
#pragma unroll
        for (int mi = 0; mi < 4; ++mi)
#pragma unroll
            for (int ni = 0; ni < 4; ++ni)
                acc[mi][ni] = __builtin_amdgcn_mfma_f32_16x16x32_bf16(
                    bb[ni], a[mi], acc[mi][ni], 0, 0, 0);
    }

#pragma unroll
    for (int mi = 0; mi < 4; ++mi) {
        const int r = rbase + wr * 64 + mi * 16 + l16;
        if (r < N_NODES) {
#pragma unroll
            for (int ni = 0; ni < 4; ++ni) {
                ushort4 o;
                o.x = f2bf(acc[mi][ni][0]);
                o.y = f2bf(acc[mi][ni][1]);
                o.z = f2bf(acc[mi][ni][2]);
                o.w = f2bf(acc[mi][ni][3]);
                const long long idx = ((long long)r * F + wc * 64 + ni * 16 + kg * 4) >> 2;
                ((ushort4*)sup)[idx] = o;
            }
        }
    }
}

// ---------- B: per-bucket deg count + local padded scan + bump-allocated CSR fill ----------
__global__ __launch_bounds__(1024) void col_fill2(const int* __restrict__ Psrc,
                                                  const unsigned short* __restrict__ Pdl,
                                                  const int* __restrict__ gcnt,
                                                  int* __restrict__ segalloc,
                                                  int* __restrict__ deg,
                                                  int* __restrict__ row_ptr,
                                                  int* __restrict__ col) {
    __shared__ int buf[SEGCAP];    // 64 KB
    __shared__ int c[BSZ];         // degree counts
    __shared__ int cnt[BSZ];       // rank counters
    __shared__ int sh[512];        // scan
    __shared__ int rp[BSZ];        // absolute segment start per node
    __shared__ int segbase_s;
    const int k = blockIdx.x;
    const int t = threadIdx.x;
    const int n0 = k * BSZ;
    const int nn = min(N_NODES - n0, BSZ);
    for (int i = t; i < BSZ; i += 1024) { c[i] = 0; cnt[i] = 0; }
    __syncthreads();
    const int e0 = k * CAP;
    const int ne = gcnt[k];
    for (int i = t; i < ne; i += 1024) atomicAdd(&c[Pdl[e0 + i]], 1);
    __syncthreads();
    // inclusive scan of padded degrees over 512 slots (nn <= 391)
    int myp = 0;
    if (t < 512) { myp = (t < nn) ? PAD8(c[t]) : 0; sh[t] = myp; }
    __syncthreads();
    for (int off = 1; off < 512; off <<= 1) {
        int u = 0;
        if (t < 512 && t >= off) u = sh[t - off];
        __syncthreads();
        if (t < 512) sh[t] += u;
        __syncthreads();
    }
    if (t == 511) segbase_s = atomicAdd(segalloc, sh[511]);
    __syncthreads();
    const int segbase = segbase_s;
    const int seglen = sh[511];                   // multiple of 8
    if (t < nn) {
        const int start = segbase + sh[t] - myp;  // exclusive prefix
        rp[t] = start;
        row_ptr[n0 + t] = start;
        deg[n0 + t] = c[t];
    }
    __syncthreads();
    for (int i = t; i < seglen; i += 1024) buf[i] = N_NODES;   // pad = zero row
    __syncthreads();
    for (int i = t; i < ne; i += 1024) {
        const int dl = Pdl[e0 + i];
        const int r = atomicAdd(&cnt[dl], 1);
        buf[rp[dl] - segbase + r] = Psrc[e0 + i];
    }
    __syncthreads();
    for (int i = t; i < (seglen >> 2); i += 1024)
        ((int4*)(col + segbase))[i] = ((const int4*)buf)[i];
}

// ---------- Kernel 5: gather-aggregate, branchless; end derived from PAD8(deg) ----------
__global__ __launch_bounds__(256) void aggregate_kernel(
    const ushort* __restrict__ sup,
    const int* __restrict__ row_ptr,
    const int* __restrict__ degv,
    const int* __restrict__ col,
    const float* __restrict__ b,
    float* __restrict__ out) {
    const int wid = threadIdx.x >> 6;
    const int lane = threadIdx.x & 63;
    const int node = blockIdx.x * 4 + wid;
    if (node >= N_NODES) return;

    const int rs = lane >> 4;   // row slot 0..3
    const int fq = lane & 15;   // feature quad

    const int beg = row_ptr[node];
    const int dg = degv[node];
    const int end = beg + PAD8(dg);

    const uint4* sp = (const uint4*)sup;

    float acc[8] = {};
    for (int base = beg; base < end; base += 64) {
        const int rem = end - base;
        const int m = rem < 64 ? rem : 64;                 // multiple of 8
        const int mycol = (lane < m) ? col[base + lane] : 0;
        const int ng16 = m >> 4;
        for (int g = 0; g < ng16; ++g) {
            uint4 v[4];
#pragma unroll
            for (int q = 0; q < 4; ++q) {
                const int s = __shfl(mycol, g * 16 + q * 4 + rs);
                v[q] = sp[(long long)s * 16 + fq];         // pads read zero row
            }
#pragma unroll
            for (int q = 0; q < 4; ++q) {
                acc[0] += blo(v[q].x); acc[1] += bhi(v[q].x);
                acc[2] += blo(v[q].y); acc[3] += bhi(v[q].y);
                acc[4] += blo(v[q].z); acc[5] += bhi(v[q].z);
                acc[6] += blo(v[q].w); acc[7] += bhi(v[q].w);
            }
        }
        if (m & 8) {                                       // 8-edge tail group
            uint4 v[2];
#pragma unroll
            for (int q = 0; q < 2; ++q) {
                const int s = __shfl(mycol, (ng16 << 4) + q * 4 + rs);
                v[q] = sp[(long long)s * 16 + fq];
            }
#pragma unroll
            for (int q = 0; q < 2; ++q) {
                acc[0] += blo(v[q].x); acc[1] += bhi(v[q].x);
                acc[2] += blo(v[q].y); acc[3] += bhi(v[q].y);
                acc[4] += blo(v[q].z); acc[5] += bhi(v[q].z);
                acc[6] += blo(v[q].w); acc[7] += bhi(v[q].w);
            }
        }
    }
    // reduce across the 4 row slots FIRST...
#pragma unroll
    for (int i = 0; i < 8; ++i) {
        acc[i] += __shfl_xor(acc[i], 16);
        acc[i] += __shfl_xor(acc[i], 32);
    }
    // ...THEN add self-loop exactly once
    {
        const uint4 v = sp[(long long)node * 16 + fq];
        acc[0] += blo(v.x); acc[1] += bhi(v.x);
        acc[2] += blo(v.y); acc[3] += bhi(v.y);
        acc[4] += blo(v.z); acc[5] += bhi(v.z);
        acc[6] += blo(v.w); acc[7] += bhi(v.w);
    }
    const float inv = 1.0f / (float)(dg + 1);
    const float4 b0 = ((const float4*)b)[fq * 2];
    const float4 b1 = ((const float4*)b)[fq * 2 + 1];
    if (rs == 0) {
        float4 r0, r1;
        r0.x = acc[0] * inv + b0.x; r0.y = acc[1] * inv + b0.y;
        r0.z = acc[2] * inv + b0.z; r0.w = acc[3] * inv + b0.w;
        r1.x = acc[4] * inv + b1.x; r1.y = acc[5] * inv + b1.y;
        r1.z = acc[6] * inv + b1.z; r1.w = acc[7] * inv + b1.w;
        float4* o4 = (float4*)out;
        o4[(long long)node * 32 + fq * 2] = r0;
        o4[(long long)node * 32 + fq * 2 + 1] = r1;
    }
}

extern "C" void kernel_launch(void* const* d_in, const int* in_sizes, int n_in,
                              void* d_out, int out_size, void* d_ws, size_t ws_size,
                              hipStream_t stream) {
    const float* x = (const float*)d_in[0];
    const int* src = (const int*)d_in[1];
    const int* dst = (const int*)d_in[2];
    const float* w = (const float*)d_in[3];
    const float* b = (const float*)d_in[4];
    float* out = (float*)d_out;

    // Workspace (~49 MB): sup 25.6 | deg .4 | row_ptr .4 | col 9.2 | Psrc 8.4 | Pdl 4.2 | wimg | ctrs
    char* p = (char*)d_ws;
    ushort* sup = (ushort*)p;    p += (((size_t)(N_NODES + 1)) * F * sizeof(ushort) + 15) & ~15ULL;
    int* deg = (int*)p;          p += ((size_t)N_NODES * sizeof(int) + 15) & ~15ULL;
    int* row_ptr = (int*)p;      p += ((size_t)N_NODES * sizeof(int) + 15) & ~15ULL;
    int* col = (int*)p;          p += ((size_t)(NE + 7 * N_NODES) * sizeof(int) + 15) & ~15ULL;
    int* Psrc = (int*)p;         p += ((size_t)NBUCK * CAP * sizeof(int) + 15) & ~15ULL;
    unsigned short* Pdl = (unsigned short*)p;  p += ((size_t)NBUCK * CAP * sizeof(unsigned short) + 15) & ~15ULL;
    ushort* wimg = (ushort*)p;   p += ((size_t)F * F * sizeof(ushort) + 15) & ~15ULL;
    int* gcnt = (int*)p;         p += ((size_t)NBUCK * sizeof(int) + 15) & ~15ULL;
    int* segalloc = (int*)p;

    prep_w<<<1, 256, 0, stream>>>(w, wimg, sup, gcnt, segalloc);
    gemm_scatter<<<NBUCK + NGEMM, 256, 0, stream>>>(x, wimg, sup, src, dst, gcnt, Psrc, Pdl);
    col_fill2<<<NBUCK, 1024, 0, stream>>>(Psrc, Pdl, gcnt, segalloc, deg, row_ptr, col);
    aggregate_kernel<<<(N_NODES + 3) / 4, 256, 0, stream>>>(sup, row_ptr, deg, col, b, out);
}